// Round 2
// baseline (1711.992 us; speedup 1.0000x reference)
//
#include <hip/hip_runtime.h>

#define B_SZ 32
#define N_TOK 4096
#define FEAT 768
#define DIM 256
#define NSLOT 16
#define NH 4
#define DH 64
#define M_TOKENS 131072
#define SCALE 0.125f
#define EPS_ATTN 1e-8f
#define MCHUNK 32768      // kv gemm M-chunk (4 chunks) -> A stays L3-warm for the GEMM

typedef unsigned short u16;
typedef __attribute__((ext_vector_type(8))) short short8;
typedef __attribute__((ext_vector_type(4))) float floatx4;

__device__ __forceinline__ u16 f2bf(float f) {
    unsigned int u = __float_as_uint(f);
    u += 0x7FFFu + ((u >> 16) & 1u);
    return (u16)(u >> 16);
}
__device__ __forceinline__ float bf2f(u16 u) {
    return __uint_as_float(((unsigned int)u) << 16);
}
__device__ __forceinline__ void gl_lds16(const void* g, void* l) {
    __builtin_amdgcn_global_load_lds((const __attribute__((address_space(1))) void*)g,
                                     (__attribute__((address_space(3))) void*)l, 16, 0, 0);
}
__device__ __forceinline__ float sigm(float x) { return 1.f / (1.f + expf(-x)); }

// ============ generic bf16 MFMA GEMM: C[M,N] = A[M,K] @ B[N,K]^T ============
// EPI 0 (KV projection, chunked): ldc carries the chunk token offset (moff).
//   n0<256 -> K written [moff+tok][256]; n0>=256 -> V written TRANSPOSED to
//   vT[b*256+c][4096] via LDS, plus column sums atomically into out2 (=vsum).
template<int TK, int EPI>
__global__ __launch_bounds__(256) void gemm_bt(
    const u16* __restrict__ A0, const u16* __restrict__ A1,
    const u16* __restrict__ B0, const u16* __restrict__ B1,
    void* __restrict__ C0, void* __restrict__ C1,
    const float* __restrict__ bias, const float* __restrict__ res,
    float* __restrict__ out2, int ldc) {
    __shared__ union SMem {
        u16 ab[2][128 * 32];   // A-stage | B-stage (K-loop)
        u16 tr[64 * 136];      // V-transpose staging (epilogue only)
    } sm;
    u16* As = sm.ab[0];
    u16* Bs = sm.ab[1];
    int t = threadIdx.x, w = t >> 6, lane = t & 63;
    int n0 = blockIdx.x * 128;
    size_t m0 = (size_t)blockIdx.y * 128;
    const u16* A = (blockIdx.z && A1) ? A1 : A0;
    const u16* B = (blockIdx.z && B1) ? B1 : B0;

    floatx4 acc[2][8];
#pragma unroll
    for (int mt = 0; mt < 2; ++mt)
#pragma unroll
        for (int nt = 0; nt < 8; ++nt) acc[mt][nt] = (floatx4)(0.f);

    int srow = (lane >> 2), seg = lane & 3;
    for (int k0 = 0; k0 < TK; k0 += 32) {
#pragma unroll
        for (int c = 0; c < 2; ++c) {
            int row = w * 32 + c * 16 + srow;
            gl_lds16(A + (m0 + row) * TK + k0 + seg * 8, &As[(w * 32 + c * 16) * 32]);
            gl_lds16(B + (size_t)(n0 + row) * TK + k0 + seg * 8, &Bs[(w * 32 + c * 16) * 32]);
        }
        __syncthreads();
        short8 af[2];
#pragma unroll
        for (int mt = 0; mt < 2; ++mt)
            af[mt] = *(const short8*)&As[(w * 32 + mt * 16 + (lane & 15)) * 32 + (lane >> 4) * 8];
        short8 bfr[8];
#pragma unroll
        for (int nt = 0; nt < 8; ++nt)
            bfr[nt] = *(const short8*)&Bs[(nt * 16 + (lane & 15)) * 32 + (lane >> 4) * 8];
#pragma unroll
        for (int mt = 0; mt < 2; ++mt)
#pragma unroll
            for (int nt = 0; nt < 8; ++nt)
                acc[mt][nt] = __builtin_amdgcn_mfma_f32_16x16x32_bf16(af[mt], bfr[nt], acc[mt][nt], 0, 0, 0);
        __syncthreads();
    }

    if (EPI == 0 && n0 >= 256) {
        // -------- V half: transpose 128x128 tile via LDS, store to vT, fuse vsum --------
        int tok0 = ldc + (int)m0;           // global token index of this tile
        int b = tok0 >> 12, jb0 = tok0 & 4095;
        int cb = n0 - 256;
        u16* vt = (u16*)C1;
#pragma unroll
        for (int pass = 0; pass < 2; ++pass) {
            __syncthreads();
#pragma unroll
            for (int mt = 0; mt < 2; ++mt)
#pragma unroll
                for (int q = 0; q < 4; ++q) {
                    int nt = pass * 4 + q;
#pragma unroll
                    for (int rr = 0; rr < 4; ++rr) {
                        int row = w * 32 + mt * 16 + (lane >> 4) * 4 + rr;
                        sm.tr[(q * 16 + (lane & 15)) * 136 + row] = f2bf(acc[mt][nt][rr]);
                    }
                }
            __syncthreads();
            int cl = t >> 2, js = (t & 3) * 32;            // 64 cols x 4 j-segments of 32
            const u16* src = &sm.tr[cl * 136 + js];
            float s = 0.f;
#pragma unroll
            for (int qi = 0; qi < 32; ++qi) s += bf2f(src[qi]);
            u16* dst = vt + ((size_t)(b * 256 + cb + pass * 64 + cl)) * 4096 + jb0 + js;
#pragma unroll
            for (int qi = 0; qi < 4; ++qi)
                *(uint4*)(dst + qi * 8) = *(const uint4*)(src + qi * 8);
            atomicAdd(&out2[b * 256 + cb + pass * 64 + cl], s);
        }
        return;
    }

#pragma unroll
    for (int mt = 0; mt < 2; ++mt)
#pragma unroll
        for (int nt = 0; nt < 8; ++nt)
#pragma unroll
            for (int rr = 0; rr < 4; ++rr) {
                size_t row = m0 + w * 32 + mt * 16 + (lane >> 4) * 4 + rr;
                int col = n0 + nt * 16 + (lane & 15);
                float v = acc[mt][nt][rr];
                if (EPI == 0) {
                    ((u16*)C0)[((size_t)ldc + row) * 256 + col] = f2bf(v);  // K half
                } else if (EPI == 1) {
                    ((u16*)C0)[row * (size_t)ldc + col] = f2bf(v);
                } else if (EPI == 2) {
                    float* Cf = (float*)(blockIdx.z ? C1 : C0);
                    Cf[row * (size_t)ldc + col] = v;
                } else if (EPI == 3) {
                    float a = v + bias[col];
                    float g = 0.5f * a * (1.f + erff(a * 0.70710678118654752f));
                    ((u16*)C0)[row * (size_t)ldc + col] = f2bf(g);
                } else if (EPI == 4) {
                    float a = v + bias[col] + res[row * 256 + col];
                    ((float*)C0)[row * 256 + col] = a;
                    out2[row * 256 + col] = a;
                }
            }
}

// ============ LN(inputs) -> bf16, one wave per row ============
__global__ __launch_bounds__(256) void k_ln_bf16(const float* __restrict__ x,
                                                 const float* __restrict__ lg,
                                                 const float* __restrict__ lb,
                                                 u16* __restrict__ xln) {
    int w = threadIdx.x >> 6, lane = threadIdx.x & 63;
    size_t row = (size_t)blockIdx.x * 4 + w;
    const float4* x4 = (const float4*)(x + row * FEAT);
    float4 a[3];
    float s = 0.f, sq = 0.f;
#pragma unroll
    for (int p = 0; p < 3; ++p) {
        a[p] = x4[p * 64 + lane];
        s += a[p].x + a[p].y + a[p].z + a[p].w;
        sq += a[p].x * a[p].x + a[p].y * a[p].y + a[p].z * a[p].z + a[p].w * a[p].w;
    }
#pragma unroll
    for (int off = 32; off >= 1; off >>= 1) {
        s += __shfl_xor(s, off);
        sq += __shfl_xor(sq, off);
    }
    float m = s * (1.f / 768.f);
    float rs = rsqrtf(sq * (1.f / 768.f) - m * m + 1e-5f);
#pragma unroll
    for (int p = 0; p < 3; ++p) {
        float4 g = *(const float4*)(lg + (p * 64 + lane) * 4);
        float4 b = *(const float4*)(lb + (p * 64 + lane) * 4);
        ushort4 o;
        o.x = f2bf((a[p].x - m) * rs * g.x + b.x);
        o.y = f2bf((a[p].y - m) * rs * g.y + b.y);
        o.z = f2bf((a[p].z - m) * rs * g.z + b.z);
        o.w = f2bf((a[p].w - m) * rs * g.w + b.w);
        *(ushort4*)(xln + row * FEAT + (p * 64 + lane) * 4) = o;
    }
}

// ============ weight convert -> bf16 (+ zero vsum for the fused epilogue) ============
#define OFF_WKV 0
#define OFF_WQ  393216
#define OFF_WIH 458752
#define OFF_WHH 655360
#define OFF_W1  851968
#define OFF_W2  1114112
#define W_TOTAL 1376256
__global__ __launch_bounds__(256) void k_wcvt(
    const float* __restrict__ wk, const float* __restrict__ wv,
    const float* __restrict__ wq, const float* __restrict__ wih,
    const float* __restrict__ whh, const float* __restrict__ w1,
    const float* __restrict__ w2, u16* __restrict__ wall,
    float* __restrict__ vsum) {
    if (blockIdx.x < 8) {
        float4 z; z.x = z.y = z.z = z.w = 0.f;
        *(float4*)(vsum + ((size_t)blockIdx.x * 256 + threadIdx.x) * 4) = z;
    }
    int base = (blockIdx.x * 256 + threadIdx.x) * 4;
    if (base >= W_TOTAL) return;
#pragma unroll
    for (int q = 0; q < 4; ++q) {
        int id = base + q;
        float v;
        if (id < OFF_WQ) {
            int r = id / 768, c = id - r * 768;
            v = (r < 256) ? wk[r * 768 + c] : wv[(r - 256) * 768 + c];
        } else if (id < OFF_WIH) v = wq[id - OFF_WQ] * SCALE;
        else if (id < OFF_W1)    v = (id < OFF_WHH) ? wih[id - OFF_WIH] : whh[id - OFF_WHH];
        else if (id < OFF_W2)    v = w1[id - OFF_W1];
        else                     v = w2[id - OFF_W2];
        wall[id] = f2bf(v);
    }
}

// ============ slots LN -> sln bf16, slots -> hp bf16, zero sums ============
__global__ __launch_bounds__(256) void k_slots_ln(const float* __restrict__ sp,
                                                  const float* __restrict__ lg,
                                                  const float* __restrict__ lb,
                                                  u16* __restrict__ sln, u16* __restrict__ hpb,
                                                  float* __restrict__ sums) {
    int t = threadIdx.x, w = t >> 6, lane = t & 63;
    if (blockIdx.x < 8) sums[blockIdx.x * 256 + t] = 0.f;
    int r = blockIdx.x * 4 + w;
    float4 v = *(const float4*)(sp + (size_t)r * 256 + lane * 4);
    float s1 = v.x + v.y + v.z + v.w;
    float s2 = v.x * v.x + v.y * v.y + v.z * v.z + v.w * v.w;
#pragma unroll
    for (int off = 32; off >= 1; off >>= 1) {
        s1 += __shfl_xor(s1, off);
        s2 += __shfl_xor(s2, off);
    }
    float m = s1 * (1.f / 256.f);
    float rs = rsqrtf(s2 * (1.f / 256.f) - m * m + 1e-5f);
    float4 g = *(const float4*)(lg + lane * 4);
    float4 b = *(const float4*)(lb + lane * 4);
    ushort4 o, hp;
    o.x = f2bf((v.x - m) * rs * g.x + b.x); o.y = f2bf((v.y - m) * rs * g.y + b.y);
    o.z = f2bf((v.z - m) * rs * g.z + b.z); o.w = f2bf((v.w - m) * rs * g.w + b.w);
    hp.x = f2bf(v.x); hp.y = f2bf(v.y); hp.z = f2bf(v.z); hp.w = f2bf(v.w);
    *(ushort4*)(sln + (size_t)r * 256 + lane * 4) = o;
    *(ushort4*)(hpb + (size_t)r * 256 + lane * 4) = hp;
}

// ============ dots (MFMA) + joint softmax + updates partial (MFMA, vT) ============
__global__ __launch_bounds__(256) void k_dots(const u16* __restrict__ qb,
                                              const u16* __restrict__ kb,
                                              const u16* __restrict__ vt,
                                              float* __restrict__ part,
                                              float* __restrict__ sums,
                                              float* __restrict__ out_attn, int last) {
    __shared__ float dots_s[64 * 65];
    __shared__ float attn_s[64 * 65];
    __shared__ float aout_s[64 * 16];
    int t = threadIdx.x, w = t >> 6, lane = t & 63;
    int b = blockIdx.y, jb = blockIdx.x, j0 = jb * 64;
    int h = w, i15 = lane & 15, qq = lane >> 4;

    short8 afq[2];
#pragma unroll
    for (int kf = 0; kf < 2; ++kf)
        afq[kf] = *(const short8*)(qb + (size_t)(b * 16 + i15) * 256 + h * 64 + kf * 32 + qq * 8);
#pragma unroll
    for (int jt = 0; jt < 4; ++jt) {
        floatx4 acc = (floatx4)(0.f);
#pragma unroll
        for (int kf = 0; kf < 2; ++kf) {
            short8 bf = *(const short8*)(kb + ((size_t)b * 4096 + j0 + jt * 16 + i15) * 256 + h * 64 + kf * 32 + qq * 8);
            acc = __builtin_amdgcn_mfma_f32_16x16x32_bf16(afq[kf], bf, acc, 0, 0, 0);
        }
#pragma unroll
        for (int r = 0; r < 4; ++r)
            dots_s[(jt * 16 + i15) * 65 + h * 16 + qq * 4 + r] = acc[r];
    }
    __syncthreads();
    float ssum = 0.f;
#pragma unroll
    for (int jj = 0; jj < 16; ++jj) {
        int jl = w * 16 + jj;
        float d = dots_s[jl * 65 + lane];
        float mx = d;
#pragma unroll
        for (int off = 32; off >= 1; off >>= 1) mx = fmaxf(mx, __shfl_xor(mx, off));
        float e = __expf(d - mx);
        float sm = e;
#pragma unroll
        for (int off = 32; off >= 1; off >>= 1) sm += __shfl_xor(sm, off);
        float a = e / sm;
        attn_s[jl * 65 + lane] = a;
        ssum += a;
        if (last) {
            float am = a + __shfl_xor(a, 16);
            am += __shfl_xor(am, 32);
            if (lane < 16) aout_s[jl * 16 + lane] = am * 0.25f;
        }
    }
    atomicAdd(&sums[b * 64 + lane], ssum);
    __syncthreads();
    short8 afa[2];
#pragma unroll
    for (int kf = 0; kf < 2; ++kf) {
        union { short8 s; u16 e[8]; } u;
#pragma unroll
        for (int jj = 0; jj < 8; ++jj)
            u.e[jj] = f2bf(attn_s[(kf * 32 + qq * 8 + jj) * 65 + h * 16 + i15]);
        afa[kf] = u.s;
    }
#pragma unroll
    for (int nt = 0; nt < 4; ++nt) {
        floatx4 acc = (floatx4)(0.f);
#pragma unroll
        for (int kf = 0; kf < 2; ++kf) {
            short8 bf = *(const short8*)(vt + ((size_t)b * 256 + h * 64 + nt * 16 + i15) * 4096 + j0 + kf * 32 + qq * 8);
            acc = __builtin_amdgcn_mfma_f32_16x16x32_bf16(afa[kf], bf, acc, 0, 0, 0);
        }
#pragma unroll
        for (int r = 0; r < 4; ++r)
            part[((size_t)b * 64 + jb) * 4096 + h * 1024 + (qq * 4 + r) * 64 + nt * 16 + i15] = acc[r];
    }
    if (last) {
        __syncthreads();
        int i = t >> 4, jq4 = (t & 15) * 4;
        float4 v;
        v.x = aout_s[(jq4 + 0) * 16 + i];
        v.y = aout_s[(jq4 + 1) * 16 + i];
        v.z = aout_s[(jq4 + 2) * 16 + i];
        v.w = aout_s[(jq4 + 3) * 16 + i];
        *(float4*)(out_attn + ((size_t)b * 16 + i) * 4096 + j0 + jq4) = v;
    }
}

// ============ reduce partials -> u bf16 (parallel, 512 blocks) ============
__global__ __launch_bounds__(256) void k_ured(const float* __restrict__ part,
                                              const float* __restrict__ sums,
                                              const float* __restrict__ vsum,
                                              u16* __restrict__ ub) {
    int r = blockIdx.x, t = threadIdx.x;
    int b = r >> 4;
    int c = (r & 15) * 256 + t;
    const float* pb = part + (size_t)b * 64 * 4096 + c;
    float acc = 0.f;
#pragma unroll 16
    for (int jb = 0; jb < 64; ++jb) acc += pb[(size_t)jb * 4096];
    int h = c >> 10, i = (c >> 6) & 15, d = c & 63;
    float rinv = 1.f / (sums[b * 64 + h * 16 + i] + 4096.f * EPS_ATTN);
    float vs = vsum[b * 256 + h * 64 + d];
    ub[((size_t)b * 16 + i) * 256 + h * 64 + d] = f2bf((acc + EPS_ATTN * vs) * rinv);
}

// ============ gate combine + hn + LN -> hln bf16 ============
__global__ __launch_bounds__(256) void k_gates(const float* __restrict__ gi,
                                               const float* __restrict__ gh,
                                               const float* __restrict__ sp,
                                               const float* __restrict__ bih,
                                               const float* __restrict__ bhh,
                                               const float* __restrict__ ffg,
                                               const float* __restrict__ ffb,
                                               float* __restrict__ hn_ws,
                                               u16* __restrict__ hln) {
    int t = threadIdx.x, w = t >> 6, lane = t & 63;
    int r = blockIdx.x * 4 + w;
    const float4* gi4 = (const float4*)(gi + (size_t)r * 768);
    const float4* gh4 = (const float4*)(gh + (size_t)r * 768);
    const float4* bi4 = (const float4*)bih;
    const float4* bh4 = (const float4*)bhh;
    float4 gir = gi4[lane], giz = gi4[64 + lane], gin = gi4[128 + lane];
    float4 ghr = gh4[lane], ghz = gh4[64 + lane], ghn = gh4[128 + lane];
    float4 bir = bi4[lane], biz = bi4[64 + lane], bin = bi4[128 + lane];
    float4 bhr = bh4[lane], bhz = bh4[64 + lane], bhn = bh4[128 + lane];
    float4 hp = *(const float4*)(sp + (size_t)r * 256 + lane * 4);
    float4 hn;
    {
        float rg, zg, ng;
        rg = sigm(gir.x + bir.x + ghr.x + bhr.x); zg = sigm(giz.x + biz.x + ghz.x + bhz.x);
        ng = tanhf(gin.x + bin.x + rg * (ghn.x + bhn.x)); hn.x = (1.f - zg) * ng + zg * hp.x;
        rg = sigm(gir.y + bir.y + ghr.y + bhr.y); zg = sigm(giz.y + biz.y + ghz.y + bhz.y);
        ng = tanhf(gin.y + bin.y + rg * (ghn.y + bhn.y)); hn.y = (1.f - zg) * ng + zg * hp.y;
        rg = sigm(gir.z + bir.z + ghr.z + bhr.z); zg = sigm(giz.z + biz.z + ghz.z + bhz.z);
        ng = tanhf(gin.z + bin.z + rg * (ghn.z + bhn.z)); hn.z = (1.f - zg) * ng + zg * hp.z;
        rg = sigm(gir.w + bir.w + ghr.w + bhr.w); zg = sigm(giz.w + biz.w + ghz.w + bhz.w);
        ng = tanhf(gin.w + bin.w + rg * (ghn.w + bhn.w)); hn.w = (1.f - zg) * ng + zg * hp.w;
    }
    *(float4*)(hn_ws + (size_t)r * 256 + lane * 4) = hn;
    float s1 = hn.x + hn.y + hn.z + hn.w;
    float s2 = hn.x * hn.x + hn.y * hn.y + hn.z * hn.z + hn.w * hn.w;
#pragma unroll
    for (int off = 32; off >= 1; off >>= 1) {
        s1 += __shfl_xor(s1, off);
        s2 += __shfl_xor(s2, off);
    }
    float m = s1 * (1.f / 256.f);
    float rs = rsqrtf(s2 * (1.f / 256.f) - m * m + 1e-5f);
    float4 g = *(const float4*)(ffg + lane * 4);
    float4 b = *(const float4*)(ffb + lane * 4);
    ushort4 o;
    o.x = f2bf((hn.x - m) * rs * g.x + b.x); o.y = f2bf((hn.y - m) * rs * g.y + b.y);
    o.z = f2bf((hn.z - m) * rs * g.z + b.z); o.w = f2bf((hn.w - m) * rs * g.w + b.w);
    *(ushort4*)(hln + (size_t)r * 256 + lane * 4) = o;
}

extern "C" void kernel_launch(void* const* d_in, const int* in_sizes, int n_in,
                              void* d_out, int out_size, void* d_ws, size_t ws_size,
                              hipStream_t stream) {
    const float* inputs   = (const float*)d_in[0];
    const float* cond     = (const float*)d_in[1];
    const float* to_q_w   = (const float*)d_in[2];
    const float* to_k_w   = (const float*)d_in[3];
    const float* to_v_w   = (const float*)d_in[4];
    const float* gru_w_ih = (const float*)d_in[5];
    const float* gru_w_hh = (const float*)d_in[6];
    const float* gru_b_ih = (const float*)d_in[7];
    const float* gru_b_hh = (const float*)d_in[8];
    const float* ln_in_g  = (const float*)d_in[9];
    const float* ln_in_b  = (const float*)d_in[10];
    const float* ln_sl_g  = (const float*)d_in[11];
    const float* ln_sl_b  = (const float*)d_in[12];
    const float* ff_ln_g  = (const float*)d_in[13];
    const float* ff_ln_b  = (const float*)d_in[14];
    const float* ff_w1    = (const float*)d_in[15];
    const float* ff_b1    = (const float*)d_in[16];
    const float* ff_w2    = (const float*)d_in[17];
    const float* ff_b2    = (const float*)d_in[18];

    float* out_slots = (float*)d_out;
    float* out_attn  = (float*)d_out + 131072;

    // ---- workspace carve ----
    char* p = (char*)d_ws;
    u16* kbuf = (u16*)p;                  p += (size_t)M_TOKENS * 256 * 2;  // 67.1 MB
    u16* vT   = (u16*)p;                  p += (size_t)M_TOKENS * 256 * 2;  // 67.1 MB (persists all iters)
    char* tregion = p;                    p += (size_t)M_TOKENS * 256 * 2;  // 67.1 MB: part/gi/gh
    float* part = (float*)tregion;                     // 33.55 MB
    float* gi   = (float*)(tregion + 33554432);        // 1.5 MB
    float* gh   = (float*)(tregion + 35127296);        // 1.5 MB
    u16* xln  = (u16*)p;                  p += (size_t)MCHUNK * FEAT * 2;   // 50.3 MB (per-chunk, reused)
    u16* wall = (u16*)p;                  p += (size_t)W_TOTAL * 2;
    u16* qbuf = (u16*)p;                  p += 131072 * 2;
    u16* sln  = (u16*)p;                  p += 131072 * 2;
    u16* hpb  = (u16*)p;                  p += 131072 * 2;
    u16* ub   = (u16*)p;                  p += 131072 * 2;
    u16* hln  = (u16*)p;                  p += 131072 * 2;
    u16* g1   = (u16*)p;                  p += (size_t)512 * 1024 * 2;
    float* slots_ws = (float*)p;          p += 131072 * 4;
    float* hn_ws    = (float*)p;          p += 131072 * 4;
    float* sums     = (float*)p;          p += 2048 * 4;
    float* vsum     = (float*)p;          p += 8192 * 4;

    k_wcvt<<<(W_TOTAL / 4 + 255) / 256, 256, 0, stream>>>(
        to_k_w, to_v_w, to_q_w, gru_w_ih, gru_w_hh, ff_w1, ff_w2, wall, vsum);

    // chunked LN + KV GEMM: A-chunk (50 MB) is L3-warm when the GEMM reads it.
    // V-transpose + vsum stay fused in the GEMM epilogue (no k_vt / k_vsum).
    for (int c = 0; c < 4; ++c) {
        k_ln_bf16<<<MCHUNK / 4, 256, 0, stream>>>(
            inputs + (size_t)c * MCHUNK * FEAT, ln_in_g, ln_in_b, xln);
        gemm_bt<768, 0><<<dim3(4, MCHUNK / 128, 1), 256, 0, stream>>>(
            xln, nullptr, wall + OFF_WKV, nullptr,
            kbuf, vT, nullptr, nullptr, vsum, c * MCHUNK);
    }

    for (int it = 0; it < 3; ++it) {
        const float* sp = (it == 0) ? cond : slots_ws;
        int last = (it == 2) ? 1 : 0;
        k_slots_ln<<<128, 256, 0, stream>>>(sp, ln_sl_g, ln_sl_b, sln, hpb, sums);
        gemm_bt<256, 1><<<dim3(2, 4, 1), 256, 0, stream>>>(
            sln, nullptr, wall + OFF_WQ, nullptr, qbuf, nullptr, nullptr, nullptr, nullptr, 256);
        k_dots<<<dim3(64, 32), 256, 0, stream>>>(qbuf, kbuf, vT, part, sums, out_attn, last);
        k_ured<<<512, 256, 0, stream>>>(part, sums, vsum, ub);
        gemm_bt<256, 2><<<dim3(6, 4, 2), 256, 0, stream>>>(
            ub, hpb, wall + OFF_WIH, wall + OFF_WHH, gi, gh, nullptr, nullptr, nullptr, 768);
        k_gates<<<128, 256, 0, stream>>>(gi, gh, sp, gru_b_ih, gru_b_hh,
                                         ff_ln_g, ff_ln_b, hn_ws, hln);
        gemm_bt<256, 3><<<dim3(8, 4, 1), 256, 0, stream>>>(
            hln, nullptr, wall + OFF_W1, nullptr, g1, nullptr, ff_b1, nullptr, nullptr, 1024);
        gemm_bt<1024, 4><<<dim3(2, 4, 1), 256, 0, stream>>>(
            g1, nullptr, wall + OFF_W2, nullptr, slots_ws, nullptr, ff_b2, hn_ws,
            last ? out_slots : slots_ws, 256);
    }
}

// Round 3
// 1110.705 us; speedup vs baseline: 1.5414x; 1.5414x over previous
//
#include <hip/hip_runtime.h>

#define B_SZ 32
#define N_TOK 4096
#define FEAT 768
#define DIM 256
#define NSLOT 16
#define NH 4
#define DH 64
#define M_TOKENS 131072
#define SCALE 0.125f
#define EPS_ATTN 1e-8f
#define MCHUNK 32768      // kv gemm M-chunk (4 chunks): A-chunk stays L3-warm

typedef unsigned short u16;
typedef __attribute__((ext_vector_type(8))) short short8;
typedef __attribute__((ext_vector_type(4))) float floatx4;

__device__ __forceinline__ u16 f2bf(float f) {
    unsigned int u = __float_as_uint(f);
    u += 0x7FFFu + ((u >> 16) & 1u);
    return (u16)(u >> 16);
}
__device__ __forceinline__ float bf2f(u16 u) {
    return __uint_as_float(((unsigned int)u) << 16);
}
__device__ __forceinline__ void gl_lds16(const void* g, void* l) {
    __builtin_amdgcn_global_load_lds((const __attribute__((address_space(1))) void*)g,
                                     (__attribute__((address_space(3))) void*)l, 16, 0, 0);
}
__device__ __forceinline__ float sigm(float x) { return 1.f / (1.f + expf(-x)); }

// ============ generic bf16 MFMA GEMM: C[M,N] = A[M,K] @ B[N,K]^T ============
// (round-0 structure: plain epilogues; V-transpose is a separate kernel —
//  fused-transpose-in-epilogue was a measured 2-round regression, do not re-add)
template<int TK, int EPI>
__global__ __launch_bounds__(256) void gemm_bt(
    const u16* __restrict__ A0, const u16* __restrict__ A1,
    const u16* __restrict__ B0, const u16* __restrict__ B1,
    void* __restrict__ C0, void* __restrict__ C1,
    const float* __restrict__ bias, const float* __restrict__ res,
    float* __restrict__ out2, int ldc) {
    __shared__ u16 As[128 * 32];
    __shared__ u16 Bs[128 * 32];
    int t = threadIdx.x, w = t >> 6, lane = t & 63;
    int n0 = blockIdx.x * 128;
    size_t m0 = (size_t)blockIdx.y * 128;
    const u16* A = (blockIdx.z && A1) ? A1 : A0;
    const u16* B = (blockIdx.z && B1) ? B1 : B0;

    floatx4 acc[2][8];
#pragma unroll
    for (int mt = 0; mt < 2; ++mt)
#pragma unroll
        for (int nt = 0; nt < 8; ++nt) acc[mt][nt] = (floatx4)(0.f);

    int srow = (lane >> 2), seg = lane & 3;
    for (int k0 = 0; k0 < TK; k0 += 32) {
#pragma unroll
        for (int c = 0; c < 2; ++c) {
            int row = w * 32 + c * 16 + srow;
            gl_lds16(A + (m0 + row) * TK + k0 + seg * 8, &As[(w * 32 + c * 16) * 32]);
            gl_lds16(B + (size_t)(n0 + row) * TK + k0 + seg * 8, &Bs[(w * 32 + c * 16) * 32]);
        }
        __syncthreads();
        short8 af[2];
#pragma unroll
        for (int mt = 0; mt < 2; ++mt)
            af[mt] = *(const short8*)&As[(w * 32 + mt * 16 + (lane & 15)) * 32 + (lane >> 4) * 8];
        short8 bfr[8];
#pragma unroll
        for (int nt = 0; nt < 8; ++nt)
            bfr[nt] = *(const short8*)&Bs[(nt * 16 + (lane & 15)) * 32 + (lane >> 4) * 8];
#pragma unroll
        for (int mt = 0; mt < 2; ++mt)
#pragma unroll
            for (int nt = 0; nt < 8; ++nt)
                acc[mt][nt] = __builtin_amdgcn_mfma_f32_16x16x32_bf16(af[mt], bfr[nt], acc[mt][nt], 0, 0, 0);
        __syncthreads();
    }
#pragma unroll
    for (int mt = 0; mt < 2; ++mt)
#pragma unroll
        for (int nt = 0; nt < 8; ++nt)
#pragma unroll
            for (int rr = 0; rr < 4; ++rr) {
                size_t row = m0 + w * 32 + mt * 16 + (lane >> 4) * 4 + rr;
                int col = n0 + nt * 16 + (lane & 15);
                float v = acc[mt][nt][rr];
                if (EPI == 0) {
                    if (col < 256) ((u16*)C0)[row * 256 + col] = f2bf(v);
                    else           ((u16*)C1)[row * 256 + col - 256] = f2bf(v);
                } else if (EPI == 1) {
                    ((u16*)C0)[row * (size_t)ldc + col] = f2bf(v);
                } else if (EPI == 2) {
                    float* Cf = (float*)(blockIdx.z ? C1 : C0);
                    Cf[row * (size_t)ldc + col] = v;
                } else if (EPI == 3) {
                    float a = v + bias[col];
                    float g = 0.5f * a * (1.f + erff(a * 0.70710678118654752f));
                    ((u16*)C0)[row * (size_t)ldc + col] = f2bf(g);
                } else if (EPI == 4) {
                    float a = v + bias[col] + res[row * 256 + col];
                    ((float*)C0)[row * 256 + col] = a;
                    out2[row * 256 + col] = a;
                }
            }
}

// ============ LN(inputs) -> bf16, one wave per row ============
__global__ __launch_bounds__(256) void k_ln_bf16(const float* __restrict__ x,
                                                 const float* __restrict__ lg,
                                                 const float* __restrict__ lb,
                                                 u16* __restrict__ xln) {
    int w = threadIdx.x >> 6, lane = threadIdx.x & 63;
    size_t row = (size_t)blockIdx.x * 4 + w;
    const float4* x4 = (const float4*)(x + row * FEAT);
    float4 a[3];
    float s = 0.f, sq = 0.f;
#pragma unroll
    for (int p = 0; p < 3; ++p) {
        a[p] = x4[p * 64 + lane];
        s += a[p].x + a[p].y + a[p].z + a[p].w;
        sq += a[p].x * a[p].x + a[p].y * a[p].y + a[p].z * a[p].z + a[p].w * a[p].w;
    }
#pragma unroll
    for (int off = 32; off >= 1; off >>= 1) {
        s += __shfl_xor(s, off);
        sq += __shfl_xor(sq, off);
    }
    float m = s * (1.f / 768.f);
    float rs = rsqrtf(sq * (1.f / 768.f) - m * m + 1e-5f);
#pragma unroll
    for (int p = 0; p < 3; ++p) {
        float4 g = *(const float4*)(lg + (p * 64 + lane) * 4);
        float4 b = *(const float4*)(lb + (p * 64 + lane) * 4);
        ushort4 o;
        o.x = f2bf((a[p].x - m) * rs * g.x + b.x);
        o.y = f2bf((a[p].y - m) * rs * g.y + b.y);
        o.z = f2bf((a[p].z - m) * rs * g.z + b.z);
        o.w = f2bf((a[p].w - m) * rs * g.w + b.w);
        *(ushort4*)(xln + row * FEAT + (p * 64 + lane) * 4) = o;
    }
}

// ============ weight convert -> bf16 ============
#define OFF_WKV 0
#define OFF_WQ  393216
#define OFF_WIH 458752
#define OFF_WHH 655360
#define OFF_W1  851968
#define OFF_W2  1114112
#define W_TOTAL 1376256
__global__ __launch_bounds__(256) void k_wcvt(
    const float* __restrict__ wk, const float* __restrict__ wv,
    const float* __restrict__ wq, const float* __restrict__ wih,
    const float* __restrict__ whh, const float* __restrict__ w1,
    const float* __restrict__ w2, u16* __restrict__ wall) {
    int base = (blockIdx.x * 256 + threadIdx.x) * 4;
    if (base >= W_TOTAL) return;
#pragma unroll
    for (int q = 0; q < 4; ++q) {
        int id = base + q;
        float v;
        if (id < OFF_WQ) {
            int r = id / 768, c = id - r * 768;
            v = (r < 256) ? wk[r * 768 + c] : wv[(r - 256) * 768 + c];
        } else if (id < OFF_WIH) v = wq[id - OFF_WQ] * SCALE;
        else if (id < OFF_W1)    v = (id < OFF_WHH) ? wih[id - OFF_WIH] : whh[id - OFF_WHH];
        else if (id < OFF_W2)    v = w1[id - OFF_W1];
        else                     v = w2[id - OFF_W2];
        wall[id] = f2bf(v);
    }
}

// ============ transpose v[b][j][c] -> vT[b][c][j]  (64j x 256c tiles) ============
__global__ __launch_bounds__(256) void k_vt(const u16* __restrict__ vb,
                                            u16* __restrict__ vt) {
    __shared__ u16 lds[256 * 66];
    int t = threadIdx.x;
    int b = blockIdx.y, j0 = blockIdx.x * 64;
#pragma unroll
    for (int it = 0; it < 16; ++it) {
        int flat = it * 256 + t;
        int j = flat >> 6, c4 = flat & 63;
        ushort4 vv = *(const ushort4*)(vb + ((size_t)b * 4096 + j0 + j) * 256 + c4 * 4);
        lds[(c4 * 4 + 0) * 66 + j] = vv.x;
        lds[(c4 * 4 + 1) * 66 + j] = vv.y;
        lds[(c4 * 4 + 2) * 66 + j] = vv.z;
        lds[(c4 * 4 + 3) * 66 + j] = vv.w;
    }
    __syncthreads();
#pragma unroll
    for (int it = 0; it < 8; ++it) {
        int flat = it * 256 + t;
        int d = flat >> 3, jseg = flat & 7;
        const unsigned int* s32 = (const unsigned int*)(lds + d * 66 + jseg * 8);
        uint4 o;
        o.x = s32[0]; o.y = s32[1]; o.z = s32[2]; o.w = s32[3];
        *(uint4*)(vt + ((size_t)b * 256 + d) * 4096 + j0 + jseg * 8) = o;
    }
}

// ============ vsum[b*256+c] = sum_j vT row (one wave per row) ============
__global__ __launch_bounds__(256) void k_vsum(const u16* __restrict__ vt,
                                              float* __restrict__ vsum) {
    int w = threadIdx.x >> 6, lane = threadIdx.x & 63;
    int r = blockIdx.x * 4 + w;
    const short8* row = (const short8*)(vt + (size_t)r * 4096);
    float s = 0.f;
#pragma unroll
    for (int it = 0; it < 8; ++it) {
        union { short8 v; u16 e[8]; } u;
        u.v = row[it * 64 + lane];
#pragma unroll
        for (int q = 0; q < 8; ++q) s += bf2f(u.e[q]);
    }
#pragma unroll
    for (int off = 32; off >= 1; off >>= 1) s += __shfl_xor(s, off);
    if (lane == 0) vsum[r] = s;
}

// ============ slots LN -> sln bf16, slots -> hp bf16 ============
__global__ __launch_bounds__(256) void k_slots_ln(const float* __restrict__ sp,
                                                  const float* __restrict__ lg,
                                                  const float* __restrict__ lb,
                                                  u16* __restrict__ sln, u16* __restrict__ hpb) {
    int t = threadIdx.x, w = t >> 6, lane = t & 63;
    int r = blockIdx.x * 4 + w;
    float4 v = *(const float4*)(sp + (size_t)r * 256 + lane * 4);
    float s1 = v.x + v.y + v.z + v.w;
    float s2 = v.x * v.x + v.y * v.y + v.z * v.z + v.w * v.w;
#pragma unroll
    for (int off = 32; off >= 1; off >>= 1) {
        s1 += __shfl_xor(s1, off);
        s2 += __shfl_xor(s2, off);
    }
    float m = s1 * (1.f / 256.f);
    float rs = rsqrtf(s2 * (1.f / 256.f) - m * m + 1e-5f);
    float4 g = *(const float4*)(lg + lane * 4);
    float4 b = *(const float4*)(lb + lane * 4);
    ushort4 o, hp;
    o.x = f2bf((v.x - m) * rs * g.x + b.x); o.y = f2bf((v.y - m) * rs * g.y + b.y);
    o.z = f2bf((v.z - m) * rs * g.z + b.z); o.w = f2bf((v.w - m) * rs * g.w + b.w);
    hp.x = f2bf(v.x); hp.y = f2bf(v.y); hp.z = f2bf(v.z); hp.w = f2bf(v.w);
    *(ushort4*)(sln + (size_t)r * 256 + lane * 4) = o;
    *(ushort4*)(hpb + (size_t)r * 256 + lane * 4) = hp;
}

// ============ dots (MFMA) + joint softmax + updates partial (MFMA, vT) ============
// sums: per-(b,jb) column-sum partials stored NON-atomically (reduced in k_ured).
__global__ __launch_bounds__(256) void k_dots(const u16* __restrict__ qb,
                                              const u16* __restrict__ kb,
                                              const u16* __restrict__ vt,
                                              float* __restrict__ part,
                                              float* __restrict__ sums_p,
                                              float* __restrict__ out_attn, int last) {
    __shared__ float dots_s[64 * 65];
    __shared__ float attn_s[64 * 65];
    __shared__ float aout_s[64 * 16];
    __shared__ float ssum_l[4][64];
    int t = threadIdx.x, w = t >> 6, lane = t & 63;
    int b = blockIdx.y, jb = blockIdx.x, j0 = jb * 64;
    int h = w, i15 = lane & 15, qq = lane >> 4;

    short8 afq[2];
#pragma unroll
    for (int kf = 0; kf < 2; ++kf)
        afq[kf] = *(const short8*)(qb + (size_t)(b * 16 + i15) * 256 + h * 64 + kf * 32 + qq * 8);
#pragma unroll
    for (int jt = 0; jt < 4; ++jt) {
        floatx4 acc = (floatx4)(0.f);
#pragma unroll
        for (int kf = 0; kf < 2; ++kf) {
            short8 bf = *(const short8*)(kb + ((size_t)b * 4096 + j0 + jt * 16 + i15) * 256 + h * 64 + kf * 32 + qq * 8);
            acc = __builtin_amdgcn_mfma_f32_16x16x32_bf16(afq[kf], bf, acc, 0, 0, 0);
        }
#pragma unroll
        for (int r = 0; r < 4; ++r)
            dots_s[(jt * 16 + i15) * 65 + h * 16 + qq * 4 + r] = acc[r];
    }
    __syncthreads();
    float ssum = 0.f;
#pragma unroll
    for (int jj = 0; jj < 16; ++jj) {
        int jl = w * 16 + jj;
        float d = dots_s[jl * 65 + lane];
        float mx = d;
#pragma unroll
        for (int off = 32; off >= 1; off >>= 1) mx = fmaxf(mx, __shfl_xor(mx, off));
        float e = __expf(d - mx);
        float sm = e;
#pragma unroll
        for (int off = 32; off >= 1; off >>= 1) sm += __shfl_xor(sm, off);
        float a = e / sm;
        attn_s[jl * 65 + lane] = a;
        ssum += a;
        if (last) {
            float am = a + __shfl_xor(a, 16);
            am += __shfl_xor(am, 32);
            if (lane < 16) aout_s[jl * 16 + lane] = am * 0.25f;
        }
    }
    ssum_l[w][lane] = ssum;
    __syncthreads();
    if (t < 64) {
        float tot = ssum_l[0][t] + ssum_l[1][t] + ssum_l[2][t] + ssum_l[3][t];
        sums_p[((size_t)b * 64 + jb) * 64 + t] = tot;
    }
    short8 afa[2];
#pragma unroll
    for (int kf = 0; kf < 2; ++kf) {
        union { short8 s; u16 e[8]; } u;
#pragma unroll
        for (int jj = 0; jj < 8; ++jj)
            u.e[jj] = f2bf(attn_s[(kf * 32 + qq * 8 + jj) * 65 + h * 16 + i15]);
        afa[kf] = u.s;
    }
#pragma unroll
    for (int nt = 0; nt < 4; ++nt) {
        floatx4 acc = (floatx4)(0.f);
#pragma unroll
        for (int kf = 0; kf < 2; ++kf) {
            short8 bf = *(const short8*)(vt + ((size_t)b * 256 + h * 64 + nt * 16 + i15) * 4096 + j0 + kf * 32 + qq * 8);
            acc = __builtin_amdgcn_mfma_f32_16x16x32_bf16(afa[kf], bf, acc, 0, 0, 0);
        }
#pragma unroll
        for (int r = 0; r < 4; ++r)
            part[((size_t)b * 64 + jb) * 4096 + h * 1024 + (qq * 4 + r) * 64 + nt * 16 + i15] = acc[r];
    }
    if (last) {
        __syncthreads();
        int i = t >> 4, jq4 = (t & 15) * 4;
        float4 v;
        v.x = aout_s[(jq4 + 0) * 16 + i];
        v.y = aout_s[(jq4 + 1) * 16 + i];
        v.z = aout_s[(jq4 + 2) * 16 + i];
        v.w = aout_s[(jq4 + 3) * 16 + i];
        *(float4*)(out_attn + ((size_t)b * 16 + i) * 4096 + j0 + jq4) = v;
    }
}

// ============ reduce partials -> u bf16 (parallel, 512 blocks) ============
// each wave handles one sh = h*16+i = (r&15)*4+w: reduce its 64 jb sum-partials
__global__ __launch_bounds__(256) void k_ured(const float* __restrict__ part,
                                              const float* __restrict__ sums_p,
                                              const float* __restrict__ vsum,
                                              u16* __restrict__ ub) {
    int r = blockIdx.x, t = threadIdx.x;
    int b = r >> 4;
    int c = (r & 15) * 256 + t;
    int w = t >> 6, lane = t & 63;
    int sh = (r & 15) * 4 + w;       // = (c>>10)*16 + ((c>>6)&15) for this wave
    float sv = sums_p[((size_t)b * 64 + lane) * 64 + sh];
#pragma unroll
    for (int off = 32; off >= 1; off >>= 1) sv += __shfl_xor(sv, off);
    const float* pb = part + (size_t)b * 64 * 4096 + c;
    float acc = 0.f;
#pragma unroll 16
    for (int jb = 0; jb < 64; ++jb) acc += pb[(size_t)jb * 4096];
    int h = c >> 10, i = (c >> 6) & 15, d = c & 63;
    float rinv = 1.f / (sv + 4096.f * EPS_ATTN);
    float vs = vsum[b * 256 + h * 64 + d];
    ub[((size_t)b * 16 + i) * 256 + h * 64 + d] = f2bf((acc + EPS_ATTN * vs) * rinv);
}

// ============ gate combine + hn + LN -> hln bf16 ============
__global__ __launch_bounds__(256) void k_gates(const float* __restrict__ gi,
                                               const float* __restrict__ gh,
                                               const float* __restrict__ sp,
                                               const float* __restrict__ bih,
                                               const float* __restrict__ bhh,
                                               const float* __restrict__ ffg,
                                               const float* __restrict__ ffb,
                                               float* __restrict__ hn_ws,
                                               u16* __restrict__ hln) {
    int t = threadIdx.x, w = t >> 6, lane = t & 63;
    int r = blockIdx.x * 4 + w;
    const float4* gi4 = (const float4*)(gi + (size_t)r * 768);
    const float4* gh4 = (const float4*)(gh + (size_t)r * 768);
    const float4* bi4 = (const float4*)bih;
    const float4* bh4 = (const float4*)bhh;
    float4 gir = gi4[lane], giz = gi4[64 + lane], gin = gi4[128 + lane];
    float4 ghr = gh4[lane], ghz = gh4[64 + lane], ghn = gh4[128 + lane];
    float4 bir = bi4[lane], biz = bi4[64 + lane], bin = bi4[128 + lane];
    float4 bhr = bh4[lane], bhz = bh4[64 + lane], bhn = bh4[128 + lane];
    float4 hp = *(const float4*)(sp + (size_t)r * 256 + lane * 4);
    float4 hn;
    {
        float rg, zg, ng;
        rg = sigm(gir.x + bir.x + ghr.x + bhr.x); zg = sigm(giz.x + biz.x + ghz.x + bhz.x);
        ng = tanhf(gin.x + bin.x + rg * (ghn.x + bhn.x)); hn.x = (1.f - zg) * ng + zg * hp.x;
        rg = sigm(gir.y + bir.y + ghr.y + bhr.y); zg = sigm(giz.y + biz.y + ghz.y + bhz.y);
        ng = tanhf(gin.y + bin.y + rg * (ghn.y + bhn.y)); hn.y = (1.f - zg) * ng + zg * hp.y;
        rg = sigm(gir.z + bir.z + ghr.z + bhr.z); zg = sigm(giz.z + biz.z + ghz.z + bhz.z);
        ng = tanhf(gin.z + bin.z + rg * (ghn.z + bhn.z)); hn.z = (1.f - zg) * ng + zg * hp.z;
        rg = sigm(gir.w + bir.w + ghr.w + bhr.w); zg = sigm(giz.w + biz.w + ghz.w + bhz.w);
        ng = tanhf(gin.w + bin.w + rg * (ghn.w + bhn.w)); hn.w = (1.f - zg) * ng + zg * hp.w;
    }
    *(float4*)(hn_ws + (size_t)r * 256 + lane * 4) = hn;
    float s1 = hn.x + hn.y + hn.z + hn.w;
    float s2 = hn.x * hn.x + hn.y * hn.y + hn.z * hn.z + hn.w * hn.w;
#pragma unroll
    for (int off = 32; off >= 1; off >>= 1) {
        s1 += __shfl_xor(s1, off);
        s2 += __shfl_xor(s2, off);
    }
    float m = s1 * (1.f / 256.f);
    float rs = rsqrtf(s2 * (1.f / 256.f) - m * m + 1e-5f);
    float4 g = *(const float4*)(ffg + lane * 4);
    float4 b = *(const float4*)(ffb + lane * 4);
    ushort4 o;
    o.x = f2bf((hn.x - m) * rs * g.x + b.x); o.y = f2bf((hn.y - m) * rs * g.y + b.y);
    o.z = f2bf((hn.z - m) * rs * g.z + b.z); o.w = f2bf((hn.w - m) * rs * g.w + b.w);
    *(ushort4*)(hln + (size_t)r * 256 + lane * 4) = o;
}

extern "C" void kernel_launch(void* const* d_in, const int* in_sizes, int n_in,
                              void* d_out, int out_size, void* d_ws, size_t ws_size,
                              hipStream_t stream) {
    const float* inputs   = (const float*)d_in[0];
    const float* cond     = (const float*)d_in[1];
    const float* to_q_w   = (const float*)d_in[2];
    const float* to_k_w   = (const float*)d_in[3];
    const float* to_v_w   = (const float*)d_in[4];
    const float* gru_w_ih = (const float*)d_in[5];
    const float* gru_w_hh = (const float*)d_in[6];
    const float* gru_b_ih = (const float*)d_in[7];
    const float* gru_b_hh = (const float*)d_in[8];
    const float* ln_in_g  = (const float*)d_in[9];
    const float* ln_in_b  = (const float*)d_in[10];
    const float* ln_sl_g  = (const float*)d_in[11];
    const float* ln_sl_b  = (const float*)d_in[12];
    const float* ff_ln_g  = (const float*)d_in[13];
    const float* ff_ln_b  = (const float*)d_in[14];
    const float* ff_w1    = (const float*)d_in[15];
    const float* ff_b1    = (const float*)d_in[16];
    const float* ff_w2    = (const float*)d_in[17];
    const float* ff_b2    = (const float*)d_in[18];

    float* out_slots = (float*)d_out;
    float* out_attn  = (float*)d_out + 131072;

    // ---- workspace carve ----
    char* p = (char*)d_ws;
    u16* kbuf = (u16*)p;                  p += (size_t)M_TOKENS * 256 * 2;  // 67.1 MB
    char* vregion = p;                    p += (size_t)M_TOKENS * 256 * 2;  // 67.1 MB
    u16*   vbuf = (u16*)vregion;                       // kv phase + k_vt only
    float* part = (float*)vregion;                     // iters (33.55 MB), after vT built
    float* gi   = (float*)(vregion + 33554432);        // 1.5 MB
    float* gh   = (float*)(vregion + 35127296);        // 1.5 MB
    char* tregion = p;                    p += (size_t)M_TOKENS * 256 * 2;  // 67.1 MB
    u16* xln_c = (u16*)tregion;                        // kv phase (50.3 MB)
    u16* vT    = (u16*)tregion;                        // after kv phase
    u16* wall = (u16*)p;                  p += (size_t)W_TOTAL * 2;
    u16* qbuf = (u16*)p;                  p += 131072 * 2;
    u16* sln  = (u16*)p;                  p += 131072 * 2;
    u16* hpb  = (u16*)p;                  p += 131072 * 2;
    u16* ub   = (u16*)p;                  p += 131072 * 2;
    u16* hln  = (u16*)p;                  p += 131072 * 2;
    u16* g1   = (u16*)p;                  p += (size_t)512 * 1024 * 2;
    float* slots_ws = (float*)p;          p += 131072 * 4;
    float* hn_ws    = (float*)p;          p += 131072 * 4;
    float* sums_p   = (float*)p;          p += (size_t)32 * 64 * 64 * 4;   // 512 KB
    float* vsum     = (float*)p;          p += 8192 * 4;

    k_wcvt<<<(W_TOTAL / 4 + 255) / 256, 256, 0, stream>>>(
        to_k_w, to_v_w, to_q_w, gru_w_ih, gru_w_hh, ff_w1, ff_w2, wall);

    for (int c = 0; c < 4; ++c) {
        k_ln_bf16<<<MCHUNK / 4, 256, 0, stream>>>(
            inputs + (size_t)c * MCHUNK * FEAT, ln_in_g, ln_in_b, xln_c);
        gemm_bt<768, 0><<<dim3(4, MCHUNK / 128, 1), 256, 0, stream>>>(
            xln_c, nullptr, wall + OFF_WKV, nullptr,
            kbuf + (size_t)c * MCHUNK * 256, vbuf + (size_t)c * MCHUNK * 256,
            nullptr, nullptr, nullptr, 256);
    }
    k_vt<<<dim3(64, 32), 256, 0, stream>>>(vbuf, vT);   // vbuf dead after this
    k_vsum<<<2048, 256, 0, stream>>>(vT, vsum);         // 8192 rows / 4 per block (grid FIXED)

    for (int it = 0; it < 3; ++it) {
        const float* sp = (it == 0) ? cond : slots_ws;
        int last = (it == 2) ? 1 : 0;
        k_slots_ln<<<128, 256, 0, stream>>>(sp, ln_sl_g, ln_sl_b, sln, hpb);
        gemm_bt<256, 1><<<dim3(2, 4, 1), 256, 0, stream>>>(
            sln, nullptr, wall + OFF_WQ, nullptr, qbuf, nullptr, nullptr, nullptr, nullptr, 256);
        k_dots<<<dim3(64, 32), 256, 0, stream>>>(qbuf, kbuf, vT, part, sums_p, out_attn, last);
        k_ured<<<512, 256, 0, stream>>>(part, sums_p, vsum, ub);
        gemm_bt<256, 2><<<dim3(6, 4, 2), 256, 0, stream>>>(
            ub, hpb, wall + OFF_WIH, wall + OFF_WHH, gi, gh, nullptr, nullptr, nullptr, 768);
        k_gates<<<128, 256, 0, stream>>>(gi, gh, sp, gru_b_ih, gru_b_hh,
                                         ff_ln_g, ff_ln_b, hn_ws, hln);
        gemm_bt<256, 3><<<dim3(8, 4, 1), 256, 0, stream>>>(
            hln, nullptr, wall + OFF_W1, nullptr, g1, nullptr, ff_b1, nullptr, nullptr, 1024);
        gemm_bt<1024, 4><<<dim3(2, 4, 1), 256, 0, stream>>>(
            g1, nullptr, wall + OFF_W2, nullptr, slots_ws, nullptr, ff_b2, hn_ws,
            last ? out_slots : slots_ws, 256);
    }
}

// Round 4
// 1077.046 us; speedup vs baseline: 1.5895x; 1.0313x over previous
//
#include <hip/hip_runtime.h>

#define B_SZ 32
#define N_TOK 4096
#define FEAT 768
#define DIM 256
#define NSLOT 16
#define NH 4
#define DH 64
#define M_TOKENS 131072
#define SCALE 0.125f
#define EPS_ATTN 1e-8f
#define MCHUNK 32768      // kv gemm M-chunk (4 chunks): A-chunk stays L3-warm

typedef unsigned short u16;
typedef __attribute__((ext_vector_type(8))) short short8;
typedef __attribute__((ext_vector_type(4))) float floatx4;

__device__ __forceinline__ u16 f2bf(float f) {
    unsigned int u = __float_as_uint(f);
    u += 0x7FFFu + ((u >> 16) & 1u);
    return (u16)(u >> 16);
}
__device__ __forceinline__ float bf2f(u16 u) {
    return __uint_as_float(((unsigned int)u) << 16);
}
__device__ __forceinline__ void gl_lds16(const void* g, void* l) {
    __builtin_amdgcn_global_load_lds((const __attribute__((address_space(1))) void*)g,
                                     (__attribute__((address_space(3))) void*)l, 16, 0, 0);
}
__device__ __forceinline__ float sigm(float x) { return 1.f / (1.f + expf(-x)); }

// ============ generic bf16 MFMA GEMM: C[M,N] = A[M,K] @ B[N,K]^T ============
// EPI 0 (KV projection): bijective XCD swizzle (grid is (4,256) -> nwg=1024,
// 1024%8==0). The 4 n-blocks sharing one 128-row A-panel become consecutive
// on ONE XCD and co-resident -> A-panel read once into that XCD's L2 instead
// of 4 separate L3 fetches on 4 XCDs. (Isolated T1; round-1 bundled it with
// the fused-transpose epilogue which was the actual regression.)
template<int TK, int EPI>
__global__ __launch_bounds__(256) void gemm_bt(
    const u16* __restrict__ A0, const u16* __restrict__ A1,
    const u16* __restrict__ B0, const u16* __restrict__ B1,
    void* __restrict__ C0, void* __restrict__ C1,
    const float* __restrict__ bias, const float* __restrict__ res,
    float* __restrict__ out2, int ldc) {
    __shared__ u16 As[128 * 32];
    __shared__ u16 Bs[128 * 32];
    int t = threadIdx.x, w = t >> 6, lane = t & 63;
    int bx = blockIdx.x, by = blockIdx.y;
    if (EPI == 0) {
        // grid (4,256): flat in [0,1024). xcd = flat&7 (round-robin dispatch),
        // idx = flat>>3 in [0,128). lg = xcd*128+idx; panel p = lg>>2 gets its
        // 4 n-blocks at lg=4p..4p+3, i.e. flats {(4p%128+n)*8 + 4p/128} -- all
        // congruent mod 8 -> same XCD, dispatched adjacently -> co-resident.
        int flat = by * 4 + bx;
        int lg = (flat & 7) * 128 + (flat >> 3);
        by = lg >> 2;
        bx = lg & 3;
    }
    int n0 = bx * 128;
    size_t m0 = (size_t)by * 128;
    const u16* A = (blockIdx.z && A1) ? A1 : A0;
    const u16* B = (blockIdx.z && B1) ? B1 : B0;

    floatx4 acc[2][8];
#pragma unroll
    for (int mt = 0; mt < 2; ++mt)
#pragma unroll
        for (int nt = 0; nt < 8; ++nt) acc[mt][nt] = (floatx4)(0.f);

    int srow = (lane >> 2), seg = lane & 3;
    for (int k0 = 0; k0 < TK; k0 += 32) {
#pragma unroll
        for (int c = 0; c < 2; ++c) {
            int row = w * 32 + c * 16 + srow;
            gl_lds16(A + (m0 + row) * TK + k0 + seg * 8, &As[(w * 32 + c * 16) * 32]);
            gl_lds16(B + (size_t)(n0 + row) * TK + k0 + seg * 8, &Bs[(w * 32 + c * 16) * 32]);
        }
        __syncthreads();
        short8 af[2];
#pragma unroll
        for (int mt = 0; mt < 2; ++mt)
            af[mt] = *(const short8*)&As[(w * 32 + mt * 16 + (lane & 15)) * 32 + (lane >> 4) * 8];
        short8 bfr[8];
#pragma unroll
        for (int nt = 0; nt < 8; ++nt)
            bfr[nt] = *(const short8*)&Bs[(nt * 16 + (lane & 15)) * 32 + (lane >> 4) * 8];
#pragma unroll
        for (int mt = 0; mt < 2; ++mt)
#pragma unroll
            for (int nt = 0; nt < 8; ++nt)
                acc[mt][nt] = __builtin_amdgcn_mfma_f32_16x16x32_bf16(af[mt], bfr[nt], acc[mt][nt], 0, 0, 0);
        __syncthreads();
    }
#pragma unroll
    for (int mt = 0; mt < 2; ++mt)
#pragma unroll
        for (int nt = 0; nt < 8; ++nt)
#pragma unroll
            for (int rr = 0; rr < 4; ++rr) {
                size_t row = m0 + w * 32 + mt * 16 + (lane >> 4) * 4 + rr;
                int col = n0 + nt * 16 + (lane & 15);
                float v = acc[mt][nt][rr];
                if (EPI == 0) {
                    if (col < 256) ((u16*)C0)[row * 256 + col] = f2bf(v);
                    else           ((u16*)C1)[row * 256 + col - 256] = f2bf(v);
                } else if (EPI == 1) {
                    ((u16*)C0)[row * (size_t)ldc + col] = f2bf(v);
                } else if (EPI == 2) {
                    float* Cf = (float*)(blockIdx.z ? C1 : C0);
                    Cf[row * (size_t)ldc + col] = v;
                } else if (EPI == 3) {
                    float a = v + bias[col];
                    float g = 0.5f * a * (1.f + erff(a * 0.70710678118654752f));
                    ((u16*)C0)[row * (size_t)ldc + col] = f2bf(g);
                } else if (EPI == 4) {
                    float a = v + bias[col] + res[row * 256 + col];
                    ((float*)C0)[row * 256 + col] = a;
                    out2[row * 256 + col] = a;
                }
            }
}

// ============ LN(inputs) -> bf16, one wave per row ============
__global__ __launch_bounds__(256) void k_ln_bf16(const float* __restrict__ x,
                                                 const float* __restrict__ lg,
                                                 const float* __restrict__ lb,
                                                 u16* __restrict__ xln) {
    int w = threadIdx.x >> 6, lane = threadIdx.x & 63;
    size_t row = (size_t)blockIdx.x * 4 + w;
    const float4* x4 = (const float4*)(x + row * FEAT);
    float4 a[3];
    float s = 0.f, sq = 0.f;
#pragma unroll
    for (int p = 0; p < 3; ++p) {
        a[p] = x4[p * 64 + lane];
        s += a[p].x + a[p].y + a[p].z + a[p].w;
        sq += a[p].x * a[p].x + a[p].y * a[p].y + a[p].z * a[p].z + a[p].w * a[p].w;
    }
#pragma unroll
    for (int off = 32; off >= 1; off >>= 1) {
        s += __shfl_xor(s, off);
        sq += __shfl_xor(sq, off);
    }
    float m = s * (1.f / 768.f);
    float rs = rsqrtf(sq * (1.f / 768.f) - m * m + 1e-5f);
#pragma unroll
    for (int p = 0; p < 3; ++p) {
        float4 g = *(const float4*)(lg + (p * 64 + lane) * 4);
        float4 b = *(const float4*)(lb + (p * 64 + lane) * 4);
        ushort4 o;
        o.x = f2bf((a[p].x - m) * rs * g.x + b.x);
        o.y = f2bf((a[p].y - m) * rs * g.y + b.y);
        o.z = f2bf((a[p].z - m) * rs * g.z + b.z);
        o.w = f2bf((a[p].w - m) * rs * g.w + b.w);
        *(ushort4*)(xln + row * FEAT + (p * 64 + lane) * 4) = o;
    }
}

// ============ weight convert -> bf16 ============
#define OFF_WKV 0
#define OFF_WQ  393216
#define OFF_WIH 458752
#define OFF_WHH 655360
#define OFF_W1  851968
#define OFF_W2  1114112
#define W_TOTAL 1376256
__global__ __launch_bounds__(256) void k_wcvt(
    const float* __restrict__ wk, const float* __restrict__ wv,
    const float* __restrict__ wq, const float* __restrict__ wih,
    const float* __restrict__ whh, const float* __restrict__ w1,
    const float* __restrict__ w2, u16* __restrict__ wall) {
    int base = (blockIdx.x * 256 + threadIdx.x) * 4;
    if (base >= W_TOTAL) return;
#pragma unroll
    for (int q = 0; q < 4; ++q) {
        int id = base + q;
        float v;
        if (id < OFF_WQ) {
            int r = id / 768, c = id - r * 768;
            v = (r < 256) ? wk[r * 768 + c] : wv[(r - 256) * 768 + c];
        } else if (id < OFF_WIH) v = wq[id - OFF_WQ] * SCALE;
        else if (id < OFF_W1)    v = (id < OFF_WHH) ? wih[id - OFF_WIH] : whh[id - OFF_WHH];
        else if (id < OFF_W2)    v = w1[id - OFF_W1];
        else                     v = w2[id - OFF_W2];
        wall[id] = f2bf(v);
    }
}

// ============ transpose v[b][j][c] -> vT[b][c][j] + vsum partials ============
__global__ __launch_bounds__(256) void k_vt(const u16* __restrict__ vb,
                                            u16* __restrict__ vt,
                                            float* __restrict__ vsum_p) {
    __shared__ u16 lds[256 * 66];
    int t = threadIdx.x;
    int b = blockIdx.y, jblk = blockIdx.x, j0 = jblk * 64;
#pragma unroll
    for (int it = 0; it < 16; ++it) {
        int flat = it * 256 + t;
        int j = flat >> 6, c4 = flat & 63;
        ushort4 vv = *(const ushort4*)(vb + ((size_t)b * 4096 + j0 + j) * 256 + c4 * 4);
        lds[(c4 * 4 + 0) * 66 + j] = vv.x;
        lds[(c4 * 4 + 1) * 66 + j] = vv.y;
        lds[(c4 * 4 + 2) * 66 + j] = vv.z;
        lds[(c4 * 4 + 3) * 66 + j] = vv.w;
    }
    __syncthreads();
    // vsum partial: thread t owns channel d=t, sums its 64 j's (lds row)
    {
        float s = 0.f;
        const u16* rowp = &lds[t * 66];
#pragma unroll
        for (int j = 0; j < 64; ++j) s += bf2f(rowp[j]);
        vsum_p[((size_t)b * 64 + jblk) * 256 + t] = s;
    }
#pragma unroll
    for (int it = 0; it < 8; ++it) {
        int flat = it * 256 + t;
        int d = flat >> 3, jseg = flat & 7;
        const unsigned int* s32 = (const unsigned int*)(lds + d * 66 + jseg * 8);
        uint4 o;
        o.x = s32[0]; o.y = s32[1]; o.z = s32[2]; o.w = s32[3];
        *(uint4*)(vt + ((size_t)b * 256 + d) * 4096 + j0 + jseg * 8) = o;
    }
}

// ============ reduce vsum partials: vsum[b*256+d] = sum_jblk partial ============
__global__ __launch_bounds__(256) void k_vsum_red(const float* __restrict__ vsum_p,
                                                  float* __restrict__ vsum) {
    int b = blockIdx.x, d = threadIdx.x;
    const float* p = vsum_p + (size_t)b * 64 * 256 + d;
    float s = 0.f;
#pragma unroll 16
    for (int jblk = 0; jblk < 64; ++jblk) s += p[jblk * 256];
    vsum[b * 256 + d] = s;
}

// ============ slots LN -> sln bf16, slots -> hp bf16 ============
__global__ __launch_bounds__(256) void k_slots_ln(const float* __restrict__ sp,
                                                  const float* __restrict__ lg,
                                                  const float* __restrict__ lb,
                                                  u16* __restrict__ sln, u16* __restrict__ hpb) {
    int t = threadIdx.x, w = t >> 6, lane = t & 63;
    int r = blockIdx.x * 4 + w;
    float4 v = *(const float4*)(sp + (size_t)r * 256 + lane * 4);
    float s1 = v.x + v.y + v.z + v.w;
    float s2 = v.x * v.x + v.y * v.y + v.z * v.z + v.w * v.w;
#pragma unroll
    for (int off = 32; off >= 1; off >>= 1) {
        s1 += __shfl_xor(s1, off);
        s2 += __shfl_xor(s2, off);
    }
    float m = s1 * (1.f / 256.f);
    float rs = rsqrtf(s2 * (1.f / 256.f) - m * m + 1e-5f);
    float4 g = *(const float4*)(lg + lane * 4);
    float4 b = *(const float4*)(lb + lane * 4);
    ushort4 o, hp;
    o.x = f2bf((v.x - m) * rs * g.x + b.x); o.y = f2bf((v.y - m) * rs * g.y + b.y);
    o.z = f2bf((v.z - m) * rs * g.z + b.z); o.w = f2bf((v.w - m) * rs * g.w + b.w);
    hp.x = f2bf(v.x); hp.y = f2bf(v.y); hp.z = f2bf(v.z); hp.w = f2bf(v.w);
    *(ushort4*)(sln + (size_t)r * 256 + lane * 4) = o;
    *(ushort4*)(hpb + (size_t)r * 256 + lane * 4) = hp;
}

// ============ dots (MFMA) + joint softmax + updates partial (MFMA, vT) ============
// sums: per-(b,jb) column-sum partials stored NON-atomically (reduced in k_ured).
__global__ __launch_bounds__(256) void k_dots(const u16* __restrict__ qb,
                                              const u16* __restrict__ kb,
                                              const u16* __restrict__ vt,
                                              float* __restrict__ part,
                                              float* __restrict__ sums_p,
                                              float* __restrict__ out_attn, int last) {
    __shared__ float dots_s[64 * 65];
    __shared__ float attn_s[64 * 65];
    __shared__ float aout_s[64 * 16];
    __shared__ float ssum_l[4][64];
    int t = threadIdx.x, w = t >> 6, lane = t & 63;
    int b = blockIdx.y, jb = blockIdx.x, j0 = jb * 64;
    int h = w, i15 = lane & 15, qq = lane >> 4;

    short8 afq[2];
#pragma unroll
    for (int kf = 0; kf < 2; ++kf)
        afq[kf] = *(const short8*)(qb + (size_t)(b * 16 + i15) * 256 + h * 64 + kf * 32 + qq * 8);
#pragma unroll
    for (int jt = 0; jt < 4; ++jt) {
        floatx4 acc = (floatx4)(0.f);
#pragma unroll
        for (int kf = 0; kf < 2; ++kf) {
            short8 bf = *(const short8*)(kb + ((size_t)b * 4096 + j0 + jt * 16 + i15) * 256 + h * 64 + kf * 32 + qq * 8);
            acc = __builtin_amdgcn_mfma_f32_16x16x32_bf16(afq[kf], bf, acc, 0, 0, 0);
        }
#pragma unroll
        for (int r = 0; r < 4; ++r)
            dots_s[(jt * 16 + i15) * 65 + h * 16 + qq * 4 + r] = acc[r];
    }
    __syncthreads();
    float ssum = 0.f;
#pragma unroll
    for (int jj = 0; jj < 16; ++jj) {
        int jl = w * 16 + jj;
        float d = dots_s[jl * 65 + lane];
        float mx = d;
#pragma unroll
        for (int off = 32; off >= 1; off >>= 1) mx = fmaxf(mx, __shfl_xor(mx, off));
        float e = __expf(d - mx);
        float sm = e;
#pragma unroll
        for (int off = 32; off >= 1; off >>= 1) sm += __shfl_xor(sm, off);
        float a = e / sm;
        attn_s[jl * 65 + lane] = a;
        ssum += a;
        if (last) {
            float am = a + __shfl_xor(a, 16);
            am += __shfl_xor(am, 32);
            if (lane < 16) aout_s[jl * 16 + lane] = am * 0.25f;
        }
    }
    ssum_l[w][lane] = ssum;
    __syncthreads();
    if (t < 64) {
        float tot = ssum_l[0][t] + ssum_l[1][t] + ssum_l[2][t] + ssum_l[3][t];
        sums_p[((size_t)b * 64 + jb) * 64 + t] = tot;
    }
    short8 afa[2];
#pragma unroll
    for (int kf = 0; kf < 2; ++kf) {
        union { short8 s; u16 e[8]; } u;
#pragma unroll
        for (int jj = 0; jj < 8; ++jj)
            u.e[jj] = f2bf(attn_s[(kf * 32 + qq * 8 + jj) * 65 + h * 16 + i15]);
        afa[kf] = u.s;
    }
#pragma unroll
    for (int nt = 0; nt < 4; ++nt) {
        floatx4 acc = (floatx4)(0.f);
#pragma unroll
        for (int kf = 0; kf < 2; ++kf) {
            short8 bf = *(const short8*)(vt + ((size_t)b * 256 + h * 64 + nt * 16 + i15) * 4096 + j0 + kf * 32 + qq * 8);
            acc = __builtin_amdgcn_mfma_f32_16x16x32_bf16(afa[kf], bf, acc, 0, 0, 0);
        }
#pragma unroll
        for (int r = 0; r < 4; ++r)
            part[((size_t)b * 64 + jb) * 4096 + h * 1024 + (qq * 4 + r) * 64 + nt * 16 + i15] = acc[r];
    }
    if (last) {
        __syncthreads();
        int i = t >> 4, jq4 = (t & 15) * 4;
        float4 v;
        v.x = aout_s[(jq4 + 0) * 16 + i];
        v.y = aout_s[(jq4 + 1) * 16 + i];
        v.z = aout_s[(jq4 + 2) * 16 + i];
        v.w = aout_s[(jq4 + 3) * 16 + i];
        *(float4*)(out_attn + ((size_t)b * 16 + i) * 4096 + j0 + jq4) = v;
    }
}

// ============ reduce partials -> u bf16 (parallel, 512 blocks) ============
// each wave handles one sh = h*16+i = (r&15)*4+w: reduce its 64 jb sum-partials
__global__ __launch_bounds__(256) void k_ured(const float* __restrict__ part,
                                              const float* __restrict__ sums_p,
                                              const float* __restrict__ vsum,
                                              u16* __restrict__ ub) {
    int r = blockIdx.x, t = threadIdx.x;
    int b = r >> 4;
    int c = (r & 15) * 256 + t;
    int w = t >> 6, lane = t & 63;
    int sh = (r & 15) * 4 + w;       // = (c>>10)*16 + ((c>>6)&15) for this wave
    float sv = sums_p[((size_t)b * 64 + lane) * 64 + sh];
#pragma unroll
    for (int off = 32; off >= 1; off >>= 1) sv += __shfl_xor(sv, off);
    const float* pb = part + (size_t)b * 64 * 4096 + c;
    float acc = 0.f;
#pragma unroll 16
    for (int jb = 0; jb < 64; ++jb) acc += pb[(size_t)jb * 4096];
    int h = c >> 10, i = (c >> 6) & 15, d = c & 63;
    float rinv = 1.f / (sv + 4096.f * EPS_ATTN);
    float vs = vsum[b * 256 + h * 64 + d];
    ub[((size_t)b * 16 + i) * 256 + h * 64 + d] = f2bf((acc + EPS_ATTN * vs) * rinv);
}

// ============ gate combine + hn + LN -> hln bf16 ============
__global__ __launch_bounds__(256) void k_gates(const float* __restrict__ gi,
                                               const float* __restrict__ gh,
                                               const float* __restrict__ sp,
                                               const float* __restrict__ bih,
                                               const float* __restrict__ bhh,
                                               const float* __restrict__ ffg,
                                               const float* __restrict__ ffb,
                                               float* __restrict__ hn_ws,
                                               u16* __restrict__ hln) {
    int t = threadIdx.x, w = t >> 6, lane = t & 63;
    int r = blockIdx.x * 4 + w;
    const float4* gi4 = (const float4*)(gi + (size_t)r * 768);
    const float4* gh4 = (const float4*)(gh + (size_t)r * 768);
    const float4* bi4 = (const float4*)bih;
    const float4* bh4 = (const float4*)bhh;
    float4 gir = gi4[lane], giz = gi4[64 + lane], gin = gi4[128 + lane];
    float4 ghr = gh4[lane], ghz = gh4[64 + lane], ghn = gh4[128 + lane];
    float4 bir = bi4[lane], biz = bi4[64 + lane], bin = bi4[128 + lane];
    float4 bhr = bh4[lane], bhz = bh4[64 + lane], bhn = bh4[128 + lane];
    float4 hp = *(const float4*)(sp + (size_t)r * 256 + lane * 4);
    float4 hn;
    {
        float rg, zg, ng;
        rg = sigm(gir.x + bir.x + ghr.x + bhr.x); zg = sigm(giz.x + biz.x + ghz.x + bhz.x);
        ng = tanhf(gin.x + bin.x + rg * (ghn.x + bhn.x)); hn.x = (1.f - zg) * ng + zg * hp.x;
        rg = sigm(gir.y + bir.y + ghr.y + bhr.y); zg = sigm(giz.y + biz.y + ghz.y + bhz.y);
        ng = tanhf(gin.y + bin.y + rg * (ghn.y + bhn.y)); hn.y = (1.f - zg) * ng + zg * hp.y;
        rg = sigm(gir.z + bir.z + ghr.z + bhr.z); zg = sigm(giz.z + biz.z + ghz.z + bhz.z);
        ng = tanhf(gin.z + bin.z + rg * (ghn.z + bhn.z)); hn.z = (1.f - zg) * ng + zg * hp.z;
        rg = sigm(gir.w + bir.w + ghr.w + bhr.w); zg = sigm(giz.w + biz.w + ghz.w + bhz.w);
        ng = tanhf(gin.w + bin.w + rg * (ghn.w + bhn.w)); hn.w = (1.f - zg) * ng + zg * hp.w;
    }
    *(float4*)(hn_ws + (size_t)r * 256 + lane * 4) = hn;
    float s1 = hn.x + hn.y + hn.z + hn.w;
    float s2 = hn.x * hn.x + hn.y * hn.y + hn.z * hn.z + hn.w * hn.w;
#pragma unroll
    for (int off = 32; off >= 1; off >>= 1) {
        s1 += __shfl_xor(s1, off);
        s2 += __shfl_xor(s2, off);
    }
    float m = s1 * (1.f / 256.f);
    float rs = rsqrtf(s2 * (1.f / 256.f) - m * m + 1e-5f);
    float4 g = *(const float4*)(ffg + lane * 4);
    float4 b = *(const float4*)(ffb + lane * 4);
    ushort4 o;
    o.x = f2bf((hn.x - m) * rs * g.x + b.x); o.y = f2bf((hn.y - m) * rs * g.y + b.y);
    o.z = f2bf((hn.z - m) * rs * g.z + b.z); o.w = f2bf((hn.w - m) * rs * g.w + b.w);
    *(ushort4*)(hln + (size_t)r * 256 + lane * 4) = o;
}

extern "C" void kernel_launch(void* const* d_in, const int* in_sizes, int n_in,
                              void* d_out, int out_size, void* d_ws, size_t ws_size,
                              hipStream_t stream) {
    const float* inputs   = (const float*)d_in[0];
    const float* cond     = (const float*)d_in[1];
    const float* to_q_w   = (const float*)d_in[2];
    const float* to_k_w   = (const float*)d_in[3];
    const float* to_v_w   = (const float*)d_in[4];
    const float* gru_w_ih = (const float*)d_in[5];
    const float* gru_w_hh = (const float*)d_in[6];
    const float* gru_b_ih = (const float*)d_in[7];
    const float* gru_b_hh = (const float*)d_in[8];
    const float* ln_in_g  = (const float*)d_in[9];
    const float* ln_in_b  = (const float*)d_in[10];
    const float* ln_sl_g  = (const float*)d_in[11];
    const float* ln_sl_b  = (const float*)d_in[12];
    const float* ff_ln_g  = (const float*)d_in[13];
    const float* ff_ln_b  = (const float*)d_in[14];
    const float* ff_w1    = (const float*)d_in[15];
    const float* ff_b1    = (const float*)d_in[16];
    const float* ff_w2    = (const float*)d_in[17];
    const float* ff_b2    = (const float*)d_in[18];

    float* out_slots = (float*)d_out;
    float* out_attn  = (float*)d_out + 131072;

    // ---- workspace carve ----
    char* p = (char*)d_ws;
    u16* kbuf = (u16*)p;                  p += (size_t)M_TOKENS * 256 * 2;  // 67.1 MB
    char* vregion = p;                    p += (size_t)M_TOKENS * 256 * 2;  // 67.1 MB
    u16*   vbuf = (u16*)vregion;                       // kv phase + k_vt only
    float* part = (float*)vregion;                     // iters (33.55 MB), after vT built
    float* gi   = (float*)(vregion + 33554432);        // 1.5 MB
    float* gh   = (float*)(vregion + 35127296);        // 1.5 MB
    char* tregion = p;                    p += (size_t)M_TOKENS * 256 * 2;  // 67.1 MB
    u16* xln_c = (u16*)tregion;                        // kv phase (50.3 MB)
    u16* vT    = (u16*)tregion;                        // after kv phase
    u16* wall = (u16*)p;                  p += (size_t)W_TOTAL * 2;
    u16* qbuf = (u16*)p;                  p += 131072 * 2;
    u16* sln  = (u16*)p;                  p += 131072 * 2;
    u16* hpb  = (u16*)p;                  p += 131072 * 2;
    u16* ub   = (u16*)p;                  p += 131072 * 2;
    u16* hln  = (u16*)p;                  p += 131072 * 2;
    u16* g1   = (u16*)p;                  p += (size_t)512 * 1024 * 2;
    float* slots_ws = (float*)p;          p += 131072 * 4;
    float* hn_ws    = (float*)p;          p += 131072 * 4;
    float* sums_p   = (float*)p;          p += (size_t)32 * 64 * 64 * 4;   // 512 KB
    float* vsum_p   = (float*)p;          p += (size_t)32 * 64 * 256 * 4;  // 2 MB
    float* vsum     = (float*)p;          p += 8192 * 4;

    k_wcvt<<<(W_TOTAL / 4 + 255) / 256, 256, 0, stream>>>(
        to_k_w, to_v_w, to_q_w, gru_w_ih, gru_w_hh, ff_w1, ff_w2, wall);

    for (int c = 0; c < 4; ++c) {
        k_ln_bf16<<<MCHUNK / 4, 256, 0, stream>>>(
            inputs + (size_t)c * MCHUNK * FEAT, ln_in_g, ln_in_b, xln_c);
        gemm_bt<768, 0><<<dim3(4, MCHUNK / 128, 1), 256, 0, stream>>>(
            xln_c, nullptr, wall + OFF_WKV, nullptr,
            kbuf + (size_t)c * MCHUNK * 256, vbuf + (size_t)c * MCHUNK * 256,
            nullptr, nullptr, nullptr, 256);
    }
    k_vt<<<dim3(64, 32), 256, 0, stream>>>(vbuf, vT, vsum_p);  // vbuf dead after this
    k_vsum_red<<<32, 256, 0, stream>>>(vsum_p, vsum);          // 2 MB reduce

    for (int it = 0; it < 3; ++it) {
        const float* sp = (it == 0) ? cond : slots_ws;
        int last = (it == 2) ? 1 : 0;
        k_slots_ln<<<128, 256, 0, stream>>>(sp, ln_sl_g, ln_sl_b, sln, hpb);
        gemm_bt<256, 1><<<dim3(2, 4, 1), 256, 0, stream>>>(
            sln, nullptr, wall + OFF_WQ, nullptr, qbuf, nullptr, nullptr, nullptr, nullptr, 256);
        k_dots<<<dim3(64, 32), 256, 0, stream>>>(qbuf, kbuf, vT, part, sums_p, out_attn, last);
        k_ured<<<512, 256, 0, stream>>>(part, sums_p, vsum, ub);
        gemm_bt<256, 2><<<dim3(6, 4, 2), 256, 0, stream>>>(
            ub, hpb, wall + OFF_WIH, wall + OFF_WHH, gi, gh, nullptr, nullptr, nullptr, 768);
        k_gates<<<128, 256, 0, stream>>>(gi, gh, sp, gru_b_ih, gru_b_hh,
                                         ff_ln_g, ff_ln_b, hn_ws, hln);
        gemm_bt<256, 3><<<dim3(8, 4, 1), 256, 0, stream>>>(
            hln, nullptr, wall + OFF_W1, nullptr, g1, nullptr, ff_b1, nullptr, nullptr, 1024);
        gemm_bt<1024, 4><<<dim3(2, 4, 1), 256, 0, stream>>>(
            g1, nullptr, wall + OFF_W2, nullptr, slots_ws, nullptr, ff_b2, hn_ws,
            last ? out_slots : slots_ws, 256);
    }
}